// Round 10
// baseline (43.665 us; speedup 1.0000x reference)
//
#include <hip/hip_runtime.h>
#include <math.h>

#define H 64
#define W 64
#define C 256
#define NB 2
#define SS 32
#define HW (H*W)

typedef __attribute__((ext_vector_type(8))) _Float16 half8;
typedef __attribute__((ext_vector_type(2))) _Float16 half2v;

// ---- fmat body (fp64) ----
__device__ void fmat_compute(const float* __restrict__ P1f,
                             const float* __restrict__ P2f,
                             double* __restrict__ Fout, int n) {
  double p1[3][4], p2[3][4];
  for (int i = 0; i < 3; ++i)
    for (int j = 0; j < 4; ++j) {
      p1[i][j] = (double)P1f[n * 12 + i * 4 + j];
      p2[i][j] = (double)P2f[n * 12 + i * 4 + j];
    }
  double A[3][3];
  for (int i = 0; i < 3; ++i)
    for (int j = 0; j < 3; ++j) {
      double s = 0;
      for (int k = 0; k < 4; ++k) s += p1[i][k] * p1[j][k];
      A[i][j] = s;
    }
  double det = A[0][0] * (A[1][1] * A[2][2] - A[1][2] * A[2][1])
             - A[0][1] * (A[1][0] * A[2][2] - A[1][2] * A[2][0])
             + A[0][2] * (A[1][0] * A[2][1] - A[1][1] * A[2][0]);
  double id = 1.0 / det;
  double Ai[3][3];
  Ai[0][0] = (A[1][1] * A[2][2] - A[1][2] * A[2][1]) * id;
  Ai[0][1] = (A[0][2] * A[2][1] - A[0][1] * A[2][2]) * id;
  Ai[0][2] = (A[0][1] * A[1][2] - A[0][2] * A[1][1]) * id;
  Ai[1][0] = (A[1][2] * A[2][0] - A[1][0] * A[2][2]) * id;
  Ai[1][1] = (A[0][0] * A[2][2] - A[0][2] * A[2][0]) * id;
  Ai[1][2] = (A[0][2] * A[1][0] - A[0][0] * A[1][2]) * id;
  Ai[2][0] = (A[1][0] * A[2][1] - A[1][1] * A[2][0]) * id;
  Ai[2][1] = (A[0][1] * A[2][0] - A[0][0] * A[2][1]) * id;
  Ai[2][2] = (A[0][0] * A[1][1] - A[0][1] * A[1][0]) * id;
  double Pi[4][3];
  for (int i = 0; i < 4; ++i)
    for (int j = 0; j < 3; ++j) {
      double s = 0;
      for (int k = 0; k < 3; ++k) s += p1[k][i] * Ai[k][j];
      Pi[i][j] = s;
    }
  double M[3][3];
  for (int i = 0; i < 3; ++i)
    for (int j = 0; j < 3; ++j) {
      double s = 0;
      for (int k = 0; k < 4; ++k) s += p2[i][k] * Pi[k][j];
      M[i][j] = s;
    }
  double nv[4];
  {
    auto det3 = [&](int ca, int cb, int cc) {
      return p1[0][ca] * (p1[1][cb] * p1[2][cc] - p1[1][cc] * p1[2][cb])
           - p1[0][cb] * (p1[1][ca] * p1[2][cc] - p1[1][cc] * p1[2][ca])
           + p1[0][cc] * (p1[1][ca] * p1[2][cb] - p1[1][cb] * p1[2][ca]);
    };
    nv[0] =  det3(1, 2, 3);
    nv[1] = -det3(0, 2, 3);
    nv[2] =  det3(0, 1, 3);
    nv[3] = -det3(0, 1, 2);
  }
  double nn = sqrt(nv[0]*nv[0] + nv[1]*nv[1] + nv[2]*nv[2] + nv[3]*nv[3]);
  for (int i = 0; i < 4; ++i) nv[i] /= nn;
  double e2[3];
  for (int i = 0; i < 3; ++i) {
    double s = 0;
    for (int j = 0; j < 4; ++j) s += p2[i][j] * nv[j];
    e2[i] = s;
  }
  for (int j = 0; j < 3; ++j) {
    Fout[n * 9 + 0 * 3 + j] = -e2[2] * M[1][j] + e2[1] * M[2][j];
    Fout[n * 9 + 1 * 3 + j] =  e2[2] * M[0][j] - e2[0] * M[2][j];
    Fout[n * 9 + 2 * 3 + j] = -e2[1] * M[0][j] + e2[0] * M[1][j];
  }
}

// ---- Kernel 1: feat2 [N,C,H,W] -> f2t fp16 [N,HW,C]; fused fmat ------------
__global__ __launch_bounds__(256) void prep_kernel(
    const float* __restrict__ feat2,
    const float* __restrict__ P1f, const float* __restrict__ P2f,
    _Float16* __restrict__ f2t, double* __restrict__ Fd) {
  __shared__ float tile[32][33];
  const int n  = blockIdx.z;
  const int p0 = blockIdx.x * 32;
  const int c0 = blockIdx.y * 32;
  const int tx = threadIdx.x, ty = threadIdx.y;   // block (32,8)
  const float* src = feat2 + (size_t)n * (C * HW);
#pragma unroll
  for (int j = 0; j < 4; ++j) {
    int cc = c0 + ty + j * 8;
    tile[ty + j * 8][tx] = src[(size_t)cc * HW + p0 + tx];
  }
  __syncthreads();
  {
    const int tid = ty * 32 + tx;
    const int pp = tid >> 3;        // 0..31
    const int cp = tid & 7;         // 0..7
    _Float16* dst = f2t + (size_t)n * (HW * C) + (size_t)(p0 + pp) * C + c0;
#pragma unroll
    for (int jj = 0; jj < 2; ++jj) {
      const int cc = (cp + jj * 8) * 2;          // 0,2,..,30
      half2v h2;
      h2.x = (_Float16)tile[cc][pp];
      h2.y = (_Float16)tile[cc + 1][pp];
      *(half2v*)(dst + cc) = h2;
    }
  }
  if (n == 0 && blockIdx.x == 0 && blockIdx.y == 0) {
    int t = ty * 32 + tx;
    if (t < NB) fmat_compute(P1f, P2f, Fd, t);
  }
}

// ---- 32-lane-group sum: 4 DPP steps (VALU) + 1 ds_swizzle (xor16) ----------
__device__ __forceinline__ float groupsum32(float v) {
  v += __int_as_float(__builtin_amdgcn_update_dpp(
         0, __float_as_int(v), 0xB1, 0xF, 0xF, true));   // quad_perm xor1
  v += __int_as_float(__builtin_amdgcn_update_dpp(
         0, __float_as_int(v), 0x4E, 0xF, 0xF, true));   // quad_perm xor2
  v += __int_as_float(__builtin_amdgcn_update_dpp(
         0, __float_as_int(v), 0x124, 0xF, 0xF, true));  // row_ror:4
  v += __int_as_float(__builtin_amdgcn_update_dpp(
         0, __float_as_int(v), 0x128, 0xF, 0xF, true));  // row_ror:8
  v += __int_as_float(__builtin_amdgcn_ds_swizzle(
         __float_as_int(v), 0x401F));                    // xor16
  return v;
}

// ---- Kernel 2: 2 px/block, 32 lanes/px, 8 ch/lane, 2-wave S-split,
//      2-deep prefetch. XCD pinning: bid%8 = XCD -> (image, row stripe). ----
struct Stage {
  half8 a, b, c, d;
  _Float16 w00, w01, w10, w11;
};

__global__ __launch_bounds__(128) void epi_main(
    const float* __restrict__ feat1, const _Float16* __restrict__ f2t,
    const double* __restrict__ Fd, float* __restrict__ out) {
  const int tid  = threadIdx.x;
  const int lane = tid & 63;
  const int sh   = tid >> 6;                // S-half (0/1)
  const int grp  = lane >> 5;               // pixel within block (0/1)
  const int cl   = lane & 31;               // channel lane
  const int bid  = blockIdx.x;
  const int r    = bid & 7;
  const int k    = bid >> 3;                // 0..511
  const int n    = r >> 2;
  const int sub  = r & 3;                   // row stripe (1024 px)
  const int p    = sub * 1024 + k * 2 + grp;
  const int h = p >> 6, w = p & (W - 1);
  const int cb = cl * 8;                    // channel base for this lane

  // --- f1: 8 channels cb..cb+7 straight from [N,C,H,W] (read once) ---
  float f1r[8];
  {
    const float* f1b = feat1 + ((size_t)n * C + cb) * HW + p;
#pragma unroll
    for (int i = 0; i < 8; ++i) f1r[i] = f1b[(size_t)i * HW];
  }

  // --- epipolar line + endpoint pick, fp32 ---
  const double* Fdp = Fd + n * 9;
  const float F0 = (float)Fdp[0], F1 = (float)Fdp[1], F2 = (float)Fdp[2];
  const float F3 = (float)Fdp[3], F4 = (float)Fdp[4], F5 = (float)Fdp[5];
  const float F6 = (float)Fdp[6], F7 = (float)Fdp[7], F8 = (float)Fdp[8];
  const float X = w * 4.0f + 1.5f;
  const float Y = h * 4.0f + 1.5f;
  const float a = F0 * X + F1 * Y + F2;
  const float b = F3 * X + F4 * Y + F5;
  const float c = F6 * X + F7 * Y + F8;
  const float a_s = (fabsf(a) < 1e-3f) ? 1e-3f : a;
  const float b_s = (fabsf(b) < 1e-3f) ? 1e-3f : b;
  const float xmin = 1.5f, xmax = 253.5f, ymin = 1.5f, ymax = 253.5f, tol = 0.01f;
  float cx[4], cy[4];
  cx[0] = xmin;  cy[0] = -(c + a * xmin) / b_s;
  cx[1] = xmax;  cy[1] = -(c + a * xmax) / b_s;
  cx[2] = -(c + b * ymin) / a_s;  cy[2] = ymin;
  cx[3] = -(c + b * ymax) / a_s;  cy[3] = ymax;
  bool valid[4];
#pragma unroll
  for (int i = 0; i < 4; ++i)
    valid[i] = (cx[i] >= xmin - tol) && (cx[i] <= xmax + tol) &&
               (cy[i] >= ymin - tol) && (cy[i] <= ymax + tol);
#pragma unroll
  for (int i = 0; i < 4; ++i)
    if (!valid[i]) { cx[i] = xmin - 10000.0f; cy[i] = ymin - 10000.0f; }
  int pk0 = -1, pk1 = -1;
#pragma unroll
  for (int i = 0; i < 4; ++i)
    if (valid[i]) { if (pk0 < 0) pk0 = i; else if (pk1 < 0) pk1 = i; }
#pragma unroll
  for (int i = 0; i < 4; ++i)
    if (!valid[i]) { if (pk0 < 0) pk0 = i; else if (pk1 < 0) pk1 = i; }
  // endpoints in destination-pixel coords: x=(px-1.5)*0.25
  const float x0p = (cx[pk0] - 1.5f) * 0.25f;
  const float y0p = (cy[pk0] - 1.5f) * 0.25f;
  const float pdx = (cx[pk1] - 1.5f) * 0.25f - x0p;
  const float pdy = (cy[pk1] - 1.5f) * 0.25f - y0p;

  const _Float16* f2b = f2t + (size_t)n * HW * C + cb;

  float m = -1e30f, l = 0.f;
  float acc[8];
#pragma unroll
  for (int i = 0; i < 8; ++i) acc[i] = 0.f;

  // issue sample s's loads + fp16 weights into st (no use of results here)
  auto issue = [&](int s, Stage& st) {
    const float t = (float)s * (1.0f / 31.0f);
    const float x = fmaf(t, pdx, x0p);
    const float y = fmaf(t, pdy, y0p);
    const float xf = floorf(x), yf = floorf(y);
    const float wx = x - xf, wy = y - yf;
    const int x0 = (int)xf, y0 = (int)yf;
    const bool bx0 = ((unsigned)x0 < W), bx1 = ((unsigned)(x0 + 1) < W);
    const bool by0 = ((unsigned)y0 < H), by1 = ((unsigned)(y0 + 1) < H);
    const int xc0 = min(max(x0, 0), W - 1);
    const int xc1 = min(max(x0 + 1, 0), W - 1);
    const int yc0 = min(max(y0, 0), H - 1);
    const int yc1 = min(max(y0 + 1, 0), H - 1);
    const float u0 = 1.f - wx, v0 = 1.f - wy;
    st.w00 = (_Float16)(v0 * u0 * (float)(bx0 & by0));
    st.w01 = (_Float16)(v0 * wx * (float)(bx1 & by0));
    st.w10 = (_Float16)(wy * u0 * (float)(bx0 & by1));
    st.w11 = (_Float16)(wy * wx * (float)(bx1 & by1));
    const int r0 = yc0 * W, r1 = yc1 * W;
    st.a = *(const half8*)(f2b + (r0 + xc0) * C);
    st.b = *(const half8*)(f2b + (r0 + xc1) * C);
    st.c = *(const half8*)(f2b + (r1 + xc0) * C);
    st.d = *(const half8*)(f2b + (r1 + xc1) * C);
  };

  auto process = [&](const Stage& st) {
    // packed fp16 bilinear (v_pk_fma_f16)
    half8 qh = st.a * st.w00 + st.b * st.w01 + st.c * st.w10 + st.d * st.w11;
    float part = 0.f;
#pragma unroll
    for (int i = 0; i < 8; ++i) part = fmaf(f1r[i], (float)qh[i], part);
    part = groupsum32(part);

    if (__any(part > m + 8.f)) {          // defer-max, wave-uniform
      const float mn = fmaxf(m, part);
      const float sc = __expf(m - mn);
      l *= sc;
#pragma unroll
      for (int i = 0; i < 8; ++i) acc[i] *= sc;
      m = mn;
    }
    const float e = __expf(part - m);
    l += e;
#pragma unroll
    for (int i = 0; i < 8; ++i) acc[i] = fmaf(e, (float)qh[i], acc[i]);
  };

  // 16 samples for this wave's S-half; 2-deep pipeline, static slots
  const int s0 = sh * 16;
  Stage sA, sB, sC;
  issue(s0 + 0, sA);
  issue(s0 + 1, sB);
  for (int k3 = 0; k3 < 12; k3 += 3) {
    issue(s0 + k3 + 2, sC);
    process(sA);
    issue(s0 + k3 + 3, sA);
    process(sB);
    issue(s0 + k3 + 4, sB);
    process(sC);
  }
  issue(s0 + 14, sC);
  process(sA);            // s0+12
  issue(s0 + 15, sA);
  process(sB);            // s0+13
  process(sC);            // s0+14
  process(sA);            // s0+15

  // --- merge the two S-halves via LDS (exact online-softmax merge) ---
  __shared__ float lsm[64][11];
  if (sh) {
#pragma unroll
    for (int i = 0; i < 8; ++i) lsm[lane][i] = acc[i];
    lsm[lane][8] = m;
    lsm[lane][9] = l;
  }
  __syncthreads();
  if (!sh) {
    const float mo = lsm[lane][8], lo = lsm[lane][9];
    const float mf = fmaxf(m, mo);
    const float e0 = __expf(m - mf), e1 = __expf(mo - mf);
    const float L = l * e0 + lo * e1;
    const float inv = 1.0f / L;
    float* ob = out + (size_t)n * C * HW + (size_t)cb * HW + p;
#pragma unroll
    for (int i = 0; i < 8; ++i)
      ob[(size_t)i * HW] = (acc[i] * e0 + lsm[lane][i] * e1) * inv;
  }
}

extern "C" void kernel_launch(void* const* d_in, const int* in_sizes, int n_in,
                              void* d_out, int out_size, void* d_ws, size_t ws_size,
                              hipStream_t stream) {
  const float* feat1 = (const float*)d_in[0];
  const float* feat2 = (const float*)d_in[1];
  const float* P1 = (const float*)d_in[2];
  const float* P2 = (const float*)d_in[3];
  float* out = (float*)d_out;

  char* ws = (char*)d_ws;
  _Float16* f2t = (_Float16*)ws;                            // 4 MB @ 0
  double*   Fd  = (double*)(ws + (5u << 20));               // @ 5 MB

  prep_kernel<<<dim3(HW / 32, C / 32, NB), dim3(32, 8), 0, stream>>>(
      feat2, P1, P2, f2t, Fd);
  epi_main<<<NB * HW / 2, 128, 0, stream>>>(feat1, f2t, Fd, out);
}

// Round 11
// 43.101 us; speedup vs baseline: 1.0131x; 1.0131x over previous
//
#include <hip/hip_runtime.h>
#include <math.h>

#define H 64
#define W 64
#define C 256
#define NB 2
#define SS 32
#define HW (H*W)

typedef __attribute__((ext_vector_type(8))) _Float16 half8;
typedef __attribute__((ext_vector_type(2))) _Float16 half2v;

// ---- fmat body (fp64) ----
__device__ void fmat_compute(const float* __restrict__ P1f,
                             const float* __restrict__ P2f,
                             double* __restrict__ Fout, int n) {
  double p1[3][4], p2[3][4];
  for (int i = 0; i < 3; ++i)
    for (int j = 0; j < 4; ++j) {
      p1[i][j] = (double)P1f[n * 12 + i * 4 + j];
      p2[i][j] = (double)P2f[n * 12 + i * 4 + j];
    }
  double A[3][3];
  for (int i = 0; i < 3; ++i)
    for (int j = 0; j < 3; ++j) {
      double s = 0;
      for (int k = 0; k < 4; ++k) s += p1[i][k] * p1[j][k];
      A[i][j] = s;
    }
  double det = A[0][0] * (A[1][1] * A[2][2] - A[1][2] * A[2][1])
             - A[0][1] * (A[1][0] * A[2][2] - A[1][2] * A[2][0])
             + A[0][2] * (A[1][0] * A[2][1] - A[1][1] * A[2][0]);
  double id = 1.0 / det;
  double Ai[3][3];
  Ai[0][0] = (A[1][1] * A[2][2] - A[1][2] * A[2][1]) * id;
  Ai[0][1] = (A[0][2] * A[2][1] - A[0][1] * A[2][2]) * id;
  Ai[0][2] = (A[0][1] * A[1][2] - A[0][2] * A[1][1]) * id;
  Ai[1][0] = (A[1][2] * A[2][0] - A[1][0] * A[2][2]) * id;
  Ai[1][1] = (A[0][0] * A[2][2] - A[0][2] * A[2][0]) * id;
  Ai[1][2] = (A[0][2] * A[1][0] - A[0][0] * A[1][2]) * id;
  Ai[2][0] = (A[1][0] * A[2][1] - A[1][1] * A[2][0]) * id;
  Ai[2][1] = (A[0][1] * A[2][0] - A[0][0] * A[2][1]) * id;
  Ai[2][2] = (A[0][0] * A[1][1] - A[0][1] * A[1][0]) * id;
  double Pi[4][3];
  for (int i = 0; i < 4; ++i)
    for (int j = 0; j < 3; ++j) {
      double s = 0;
      for (int k = 0; k < 3; ++k) s += p1[k][i] * Ai[k][j];
      Pi[i][j] = s;
    }
  double M[3][3];
  for (int i = 0; i < 3; ++i)
    for (int j = 0; j < 3; ++j) {
      double s = 0;
      for (int k = 0; k < 4; ++k) s += p2[i][k] * Pi[k][j];
      M[i][j] = s;
    }
  double nv[4];
  {
    auto det3 = [&](int ca, int cb, int cc) {
      return p1[0][ca] * (p1[1][cb] * p1[2][cc] - p1[1][cc] * p1[2][cb])
           - p1[0][cb] * (p1[1][ca] * p1[2][cc] - p1[1][cc] * p1[2][ca])
           + p1[0][cc] * (p1[1][ca] * p1[2][cb] - p1[1][cb] * p1[2][ca]);
    };
    nv[0] =  det3(1, 2, 3);
    nv[1] = -det3(0, 2, 3);
    nv[2] =  det3(0, 1, 3);
    nv[3] = -det3(0, 1, 2);
  }
  double nn = sqrt(nv[0]*nv[0] + nv[1]*nv[1] + nv[2]*nv[2] + nv[3]*nv[3]);
  for (int i = 0; i < 4; ++i) nv[i] /= nn;
  double e2[3];
  for (int i = 0; i < 3; ++i) {
    double s = 0;
    for (int j = 0; j < 4; ++j) s += p2[i][j] * nv[j];
    e2[i] = s;
  }
  for (int j = 0; j < 3; ++j) {
    Fout[n * 9 + 0 * 3 + j] = -e2[2] * M[1][j] + e2[1] * M[2][j];
    Fout[n * 9 + 1 * 3 + j] =  e2[2] * M[0][j] - e2[0] * M[2][j];
    Fout[n * 9 + 2 * 3 + j] = -e2[1] * M[0][j] + e2[0] * M[1][j];
  }
}

// ---- Kernel 1: feat2 [N,C,H,W] -> f2t fp16 [N,HW,C]; fused fmat ------------
__global__ __launch_bounds__(256) void prep_kernel(
    const float* __restrict__ feat2,
    const float* __restrict__ P1f, const float* __restrict__ P2f,
    _Float16* __restrict__ f2t, double* __restrict__ Fd) {
  __shared__ float tile[32][33];
  const int n  = blockIdx.z;
  const int p0 = blockIdx.x * 32;
  const int c0 = blockIdx.y * 32;
  const int tx = threadIdx.x, ty = threadIdx.y;   // block (32,8)
  const float* src = feat2 + (size_t)n * (C * HW);
#pragma unroll
  for (int j = 0; j < 4; ++j) {
    int cc = c0 + ty + j * 8;
    tile[ty + j * 8][tx] = src[(size_t)cc * HW + p0 + tx];
  }
  __syncthreads();
  {
    const int tid = ty * 32 + tx;
    const int pp = tid >> 3;        // 0..31
    const int cp = tid & 7;         // 0..7
    _Float16* dst = f2t + (size_t)n * (HW * C) + (size_t)(p0 + pp) * C + c0;
#pragma unroll
    for (int jj = 0; jj < 2; ++jj) {
      const int cc = (cp + jj * 8) * 2;          // 0,2,..,30
      half2v h2;
      h2.x = (_Float16)tile[cc][pp];
      h2.y = (_Float16)tile[cc + 1][pp];
      *(half2v*)(dst + cc) = h2;
    }
  }
  if (n == 0 && blockIdx.x == 0 && blockIdx.y == 0) {
    int t = ty * 32 + tx;
    if (t < NB) fmat_compute(P1f, P2f, Fd, t);
  }
}

// ---- 32-lane-group sum: 4 DPP steps (VALU) + 1 ds_swizzle (xor16) ----------
__device__ __forceinline__ float groupsum32(float v) {
  v += __int_as_float(__builtin_amdgcn_update_dpp(
         0, __float_as_int(v), 0xB1, 0xF, 0xF, true));   // quad_perm xor1
  v += __int_as_float(__builtin_amdgcn_update_dpp(
         0, __float_as_int(v), 0x4E, 0xF, 0xF, true));   // quad_perm xor2
  v += __int_as_float(__builtin_amdgcn_update_dpp(
         0, __float_as_int(v), 0x124, 0xF, 0xF, true));  // row_ror:4
  v += __int_as_float(__builtin_amdgcn_update_dpp(
         0, __float_as_int(v), 0x128, 0xF, 0xF, true));  // row_ror:8
  v += __int_as_float(__builtin_amdgcn_ds_swizzle(
         __float_as_int(v), 0x401F));                    // xor16
  return v;
}

// ---- Kernel 2: 512-thread blocks = 16 CONSECUTIVE pixels on ONE CU ---------
// (8 waves x 2 px/wave). Adjacent pixels' epipolar lines nearly coincide, so
// their gather points share L1 lines -- co-residency on one CU harvests that.
// XCD pinning: bid%8 = XCD -> (image n, row stripe sub).
struct Stage {
  half8 a, b, c, d;
  _Float16 w00, w01, w10, w11;
};

__global__ __launch_bounds__(512) void epi_main(
    const float* __restrict__ feat1, const _Float16* __restrict__ f2t,
    const double* __restrict__ Fd, float* __restrict__ out) {
  const int tid  = threadIdx.x;
  const int lane = tid & 63;
  const int wv   = tid >> 6;                // wave 0..7
  const int grp  = lane >> 5;               // pixel within wave (0/1)
  const int cl   = lane & 31;               // channel lane
  const int bid  = blockIdx.x;
  const int r    = bid & 7;
  const int k    = bid >> 3;                // 0..63
  const int n    = r >> 2;
  const int sub  = r & 3;                   // row stripe (1024 px)
  const int p    = sub * 1024 + k * 16 + wv * 2 + grp;
  const int h = p >> 6, w = p & (W - 1);
  const int cb = cl * 8;                    // channel base for this lane

  // --- f1: 8 channels cb..cb+7 straight from [N,C,H,W] (read once) ---
  float f1r[8];
  {
    const float* f1b = feat1 + ((size_t)n * C + cb) * HW + p;
#pragma unroll
    for (int i = 0; i < 8; ++i) f1r[i] = f1b[(size_t)i * HW];
  }

  // --- epipolar line + endpoint pick, fp32 ---
  const double* Fdp = Fd + n * 9;
  const float F0 = (float)Fdp[0], F1 = (float)Fdp[1], F2 = (float)Fdp[2];
  const float F3 = (float)Fdp[3], F4 = (float)Fdp[4], F5 = (float)Fdp[5];
  const float F6 = (float)Fdp[6], F7 = (float)Fdp[7], F8 = (float)Fdp[8];
  const float X = w * 4.0f + 1.5f;
  const float Y = h * 4.0f + 1.5f;
  const float a = F0 * X + F1 * Y + F2;
  const float b = F3 * X + F4 * Y + F5;
  const float c = F6 * X + F7 * Y + F8;
  const float a_s = (fabsf(a) < 1e-3f) ? 1e-3f : a;
  const float b_s = (fabsf(b) < 1e-3f) ? 1e-3f : b;
  const float xmin = 1.5f, xmax = 253.5f, ymin = 1.5f, ymax = 253.5f, tol = 0.01f;
  float cx[4], cy[4];
  cx[0] = xmin;  cy[0] = -(c + a * xmin) / b_s;
  cx[1] = xmax;  cy[1] = -(c + a * xmax) / b_s;
  cx[2] = -(c + b * ymin) / a_s;  cy[2] = ymin;
  cx[3] = -(c + b * ymax) / a_s;  cy[3] = ymax;
  bool valid[4];
#pragma unroll
  for (int i = 0; i < 4; ++i)
    valid[i] = (cx[i] >= xmin - tol) && (cx[i] <= xmax + tol) &&
               (cy[i] >= ymin - tol) && (cy[i] <= ymax + tol);
#pragma unroll
  for (int i = 0; i < 4; ++i)
    if (!valid[i]) { cx[i] = xmin - 10000.0f; cy[i] = ymin - 10000.0f; }
  int pk0 = -1, pk1 = -1;
#pragma unroll
  for (int i = 0; i < 4; ++i)
    if (valid[i]) { if (pk0 < 0) pk0 = i; else if (pk1 < 0) pk1 = i; }
#pragma unroll
  for (int i = 0; i < 4; ++i)
    if (!valid[i]) { if (pk0 < 0) pk0 = i; else if (pk1 < 0) pk1 = i; }
  // endpoints in destination-pixel coords: x=(px-1.5)*0.25
  const float x0p = (cx[pk0] - 1.5f) * 0.25f;
  const float y0p = (cy[pk0] - 1.5f) * 0.25f;
  const float pdx = (cx[pk1] - 1.5f) * 0.25f - x0p;
  const float pdy = (cy[pk1] - 1.5f) * 0.25f - y0p;

  const _Float16* f2b = f2t + (size_t)n * HW * C + cb;

  float m = -1e30f, l = 0.f;
  float acc[8];
#pragma unroll
  for (int i = 0; i < 8; ++i) acc[i] = 0.f;

  // issue sample s's loads + fp16 weights into st (no use of results here)
  auto issue = [&](int s, Stage& st) {
    const float t = (float)s * (1.0f / 31.0f);
    const float x = fmaf(t, pdx, x0p);
    const float y = fmaf(t, pdy, y0p);
    const float xf = floorf(x), yf = floorf(y);
    const float wx = x - xf, wy = y - yf;
    const int x0 = (int)xf, y0 = (int)yf;
    const bool bx0 = ((unsigned)x0 < W), bx1 = ((unsigned)(x0 + 1) < W);
    const bool by0 = ((unsigned)y0 < H), by1 = ((unsigned)(y0 + 1) < H);
    const int xc0 = min(max(x0, 0), W - 1);
    const int xc1 = min(max(x0 + 1, 0), W - 1);
    const int yc0 = min(max(y0, 0), H - 1);
    const int yc1 = min(max(y0 + 1, 0), H - 1);
    const float u0 = 1.f - wx, v0 = 1.f - wy;
    st.w00 = (_Float16)(v0 * u0 * (float)(bx0 & by0));
    st.w01 = (_Float16)(v0 * wx * (float)(bx1 & by0));
    st.w10 = (_Float16)(wy * u0 * (float)(bx0 & by1));
    st.w11 = (_Float16)(wy * wx * (float)(bx1 & by1));
    const int r0 = yc0 * W, r1 = yc1 * W;
    st.a = *(const half8*)(f2b + (r0 + xc0) * C);
    st.b = *(const half8*)(f2b + (r0 + xc1) * C);
    st.c = *(const half8*)(f2b + (r1 + xc0) * C);
    st.d = *(const half8*)(f2b + (r1 + xc1) * C);
  };

  auto process = [&](const Stage& st) {
    // packed fp16 bilinear (v_pk_fma_f16)
    half8 qh = st.a * st.w00 + st.b * st.w01 + st.c * st.w10 + st.d * st.w11;
    float part = 0.f;
#pragma unroll
    for (int i = 0; i < 8; ++i) part = fmaf(f1r[i], (float)qh[i], part);
    part = groupsum32(part);

    if (__any(part > m + 8.f)) {          // defer-max, wave-uniform
      const float mn = fmaxf(m, part);
      const float sc = __expf(m - mn);
      l *= sc;
#pragma unroll
      for (int i = 0; i < 8; ++i) acc[i] *= sc;
      m = mn;
    }
    const float e = __expf(part - m);
    l += e;
#pragma unroll
    for (int i = 0; i < 8; ++i) acc[i] = fmaf(e, (float)qh[i], acc[i]);
  };

  // 2-deep software pipeline over all 32 samples; stage slots static
  Stage sA, sB, sC;
  issue(0, sA);
  issue(1, sB);
  for (int k3 = 0; k3 < 30; k3 += 3) {
    issue(k3 + 2, sC);
    process(sA);
    issue(k3 + 3, sA);
    process(sB);
    issue(k3 + 4, sB);
    process(sC);
  }
  process(sA);   // s = 30
  process(sB);   // s = 31

  const float inv = 1.0f / l;
  float* ob = out + (size_t)n * C * HW + (size_t)cb * HW + p;
#pragma unroll
  for (int i = 0; i < 8; ++i) ob[(size_t)i * HW] = acc[i] * inv;
}

extern "C" void kernel_launch(void* const* d_in, const int* in_sizes, int n_in,
                              void* d_out, int out_size, void* d_ws, size_t ws_size,
                              hipStream_t stream) {
  const float* feat1 = (const float*)d_in[0];
  const float* feat2 = (const float*)d_in[1];
  const float* P1 = (const float*)d_in[2];
  const float* P2 = (const float*)d_in[3];
  float* out = (float*)d_out;

  char* ws = (char*)d_ws;
  _Float16* f2t = (_Float16*)ws;                            // 4 MB @ 0
  double*   Fd  = (double*)(ws + (5u << 20));               // @ 5 MB

  prep_kernel<<<dim3(HW / 32, C / 32, NB), dim3(32, 8), 0, stream>>>(
      feat2, P1, P2, f2t, Fd);
  epi_main<<<NB * HW / 16, 512, 0, stream>>>(feat1, f2t, Fd, out);
}